// Round 3
// baseline (28.704 us; speedup 1.0000x reference)
//
#include <hip/hip_runtime.h>
#include <cmath>

// AGD loss: for each of n=32768 rows (view-major flatten of [B,2,128] features),
// evaluate the truncated Saw series at the first 100 coordinates, sum, gather
// the label coordinate's value, accumulate log(sum) - log(s_lab).
// The exp(log_Cd - 1/(2*var)) prefactor cancels between the two logs.
// NT=28 (vs reference 40): tail ~ (y*sqrt(d))^28/28! <= 7e-9 at max |y|~0.51,
// vs s >= 0.003 -> relative error ~1e-6, negligible at the 2% threshold.

#define BQ     16384   // batch
#define NROWS  32768   // V*B
#define NT     28      // truncated series terms

struct Coefs { float c[NT]; };

// 8 threads per row. Lane phase p = tid&7.
// Coords 0..95 as 24 float4 chunks: lane p owns chunks {p, p+8, p+16}.
// 13th poly: lanes p<4 evaluate coord 96+p, lanes p>=4 evaluate the label
// coord (same instruction stream, no divergence, no redundant label work).
// One atomicAdd per block into out[0] (pre-zeroed by a 4-byte memset node).
__global__ __launch_bounds__(256) void agd_loss_kernel(
    const float* __restrict__ feats,    // [B, 2, 128]
    const int*   __restrict__ labels,   // [B]
    float*       __restrict__ out,      // [1], zeroed by memset node
    Coefs C)
{
    const int tid = threadIdx.x;
    const int p   = tid & 7;
    const int j   = blockIdx.x * 32 + (tid >> 3);   // global row, 32 rows/block
    const int b   = j & (BQ - 1);
    const int v   = j >> 14;
    const float*  row  = feats + ((size_t)(b * 2 + v) << 7);
    const float4* row4 = (const float4*)row;
    const int lab = labels[b];

    float sum_s = 0.0f;
    #pragma unroll
    for (int i = 0; i < 3; ++i) {
        const float4 yv = row4[p + 8 * i];   // lanes 0..7 -> 128 contiguous B
        float s0 = C.c[NT - 1], s1 = s0, s2 = s0, s3 = s0;
        #pragma unroll
        for (int k = NT - 2; k >= 0; --k) {
            s0 = fmaf(s0, yv.x, C.c[k]);
            s1 = fmaf(s1, yv.y, C.c[k]);
            s2 = fmaf(s2, yv.z, C.c[k]);
            s3 = fmaf(s3, yv.w, C.c[k]);
        }
        sum_s += (s0 + s1) + (s2 + s3);
    }

    // 13th polynomial, balanced across lanes
    const float y13 = (p < 4) ? row[96 + p] : row[lab];
    float s13 = C.c[NT - 1];
    #pragma unroll
    for (int k = NT - 2; k >= 0; --k) s13 = fmaf(s13, y13, C.c[k]);
    if (p < 4) sum_s += s13;             // coords 96..99 join the norm sum

    // reduce sum_s across the 8 lanes of this row (bits 0..2)
    sum_s += __shfl_xor(sum_s, 1);
    sum_s += __shfl_xor(sum_s, 2);
    sum_s += __shfl_xor(sum_s, 4);

    // bring the label-poly value (held by lanes p>=4) to lanes p<4
    const float s_lab = __shfl_xor(s13, 4);

    // per-row loss term on phase-0 lanes only
    float term = (p == 0) ? (logf(sum_s) - logf(s_lab)) : 0.0f;

    // wave butterfly over the 8 rows in this wave (bits 3..5)
    term += __shfl_xor(term, 8);
    term += __shfl_xor(term, 16);
    term += __shfl_xor(term, 32);

    __shared__ float wsum[4];
    const int wave = tid >> 6;
    if ((tid & 63) == 0) wsum[wave] = term;
    __syncthreads();
    if (tid == 0) {
        atomicAdd(out, (wsum[0] + wsum[1]) + (wsum[2] + wsum[3]));
    }
}

extern "C" void kernel_launch(void* const* d_in, const int* in_sizes, int n_in,
                              void* d_out, int out_size, void* d_ws, size_t ws_size,
                              hipStream_t stream) {
    (void)in_sizes; (void)n_in; (void)out_size; (void)d_ws; (void)ws_size;
    const float* feats  = (const float*)d_in[0];
    const int*   labels = (const int*)d_in[1];
    float*       out    = (float*)d_out;

    // Saw series coefficients c_n = 2^{n/2} Gamma((d+n)/2) / Gamma(d/2) / n!,
    // d = 128, computed in double on host, passed by value (capture-safe).
    Coefs C;
    for (int n = 0; n < NT; ++n) {
        const double ln = 0.5 * n * std::log(2.0)
                        + std::lgamma((128.0 + n) / 2.0)
                        - std::lgamma(64.0)
                        - std::lgamma(n + 1.0);
        C.c[n] = (float)std::exp(ln);
    }

    hipMemsetAsync(d_out, 0, sizeof(float), stream);
    // 8 threads/row * 32768 rows / 256 threads = 1024 blocks (4 blocks/CU)
    agd_loss_kernel<<<1024, 256, 0, stream>>>(feats, labels, out, C);
}

// Round 4
// 11.017 us; speedup vs baseline: 2.6054x; 2.6054x over previous
//
#include <hip/hip_runtime.h>
#include <cmath>

// AGD loss: for each of n=32768 rows (view-major flatten of [B,2,128] features),
// evaluate the truncated Saw series at the first 100 coordinates, sum, gather
// the label coordinate's value, accumulate log(sum) - log(s_lab).
// The exp(log_Cd - 1/(2*var)) prefactor cancels between the two logs.
// NT=20 (vs reference 40): term_n ~ (y*sqrt(d))^n/n!, worst |y*sqrt(d)|~6.0
// -> tail at n=20 ~ 1.5e-3 abs vs s ~ 400 -> rel ~ 4e-6. Threshold is 2%.
//
// Structure note (round-3 lesson): NO same-address global atomics (1024 of
// them cost ~17 us serialized at L2) and no memset node. Two kernels:
// block partials -> d_ws, then a tiny tree-reduce kernel writes out[0].

#define BQ     16384   // batch
#define NROWS  32768   // V*B
#define NT     20      // truncated series terms

struct Coefs { float c[NT]; };

// 8 threads per row. Lane phase p = tid&7.
// Coords 0..95 as 24 float4 chunks: lane p owns chunks {p, p+8, p+16}.
// 13th poly: lanes p<4 evaluate coord 96+p, lanes p>=4 evaluate the label
// coord (same instruction stream, no divergence, no redundant label work).
__global__ __launch_bounds__(256) void agd_partial_kernel(
    const float* __restrict__ feats,    // [B, 2, 128]
    const int*   __restrict__ labels,   // [B]
    float*       __restrict__ partials, // [gridDim.x]
    Coefs C)
{
    const int tid = threadIdx.x;
    const int p   = tid & 7;
    const int j   = blockIdx.x * 32 + (tid >> 3);   // global row, 32 rows/block
    const int b   = j & (BQ - 1);
    const int v   = j >> 14;
    const float*  row  = feats + ((size_t)(b * 2 + v) << 7);
    const float4* row4 = (const float4*)row;
    const int lab = labels[b];

    float sum_s = 0.0f;
    #pragma unroll
    for (int i = 0; i < 3; ++i) {
        const float4 yv = row4[p + 8 * i];   // lanes 0..7 -> 128 contiguous B
        float s0 = C.c[NT - 1], s1 = s0, s2 = s0, s3 = s0;
        #pragma unroll
        for (int k = NT - 2; k >= 0; --k) {
            s0 = fmaf(s0, yv.x, C.c[k]);
            s1 = fmaf(s1, yv.y, C.c[k]);
            s2 = fmaf(s2, yv.z, C.c[k]);
            s3 = fmaf(s3, yv.w, C.c[k]);
        }
        sum_s += (s0 + s1) + (s2 + s3);
    }

    // 13th polynomial, balanced across lanes
    const float y13 = (p < 4) ? row[96 + p] : row[lab];
    float s13 = C.c[NT - 1];
    #pragma unroll
    for (int k = NT - 2; k >= 0; --k) s13 = fmaf(s13, y13, C.c[k]);
    if (p < 4) sum_s += s13;             // coords 96..99 join the norm sum

    // reduce sum_s across the 8 lanes of this row (bits 0..2)
    sum_s += __shfl_xor(sum_s, 1);
    sum_s += __shfl_xor(sum_s, 2);
    sum_s += __shfl_xor(sum_s, 4);

    // bring the label-poly value (held by lanes p>=4) to lanes p<4
    const float s_lab = __shfl_xor(s13, 4);

    // per-row loss term on phase-0 lanes only
    float term = (p == 0) ? (logf(sum_s) - logf(s_lab)) : 0.0f;

    // wave butterfly over the 8 rows in this wave (bits 3..5)
    term += __shfl_xor(term, 8);
    term += __shfl_xor(term, 16);
    term += __shfl_xor(term, 32);

    __shared__ float wsum[4];
    const int wave = tid >> 6;
    if ((tid & 63) == 0) wsum[wave] = term;
    __syncthreads();
    if (tid == 0) partials[blockIdx.x] = (wsum[0] + wsum[1]) + (wsum[2] + wsum[3]);
}

// Reduce 1024 block partials -> out[0]. Single block, one float4 per thread,
// direct store (no memset, no atomics anywhere).
__global__ __launch_bounds__(256) void agd_reduce_kernel(
    const float* __restrict__ partials, float* __restrict__ out)
{
    const int tid = threadIdx.x;
    const float4 v = ((const float4*)partials)[tid];
    float s = (v.x + v.y) + (v.z + v.w);
    s += __shfl_xor(s, 1);
    s += __shfl_xor(s, 2);
    s += __shfl_xor(s, 4);
    s += __shfl_xor(s, 8);
    s += __shfl_xor(s, 16);
    s += __shfl_xor(s, 32);
    __shared__ float w[4];
    if ((tid & 63) == 0) w[tid >> 6] = s;
    __syncthreads();
    if (tid == 0) out[0] = (w[0] + w[1]) + (w[2] + w[3]);
}

extern "C" void kernel_launch(void* const* d_in, const int* in_sizes, int n_in,
                              void* d_out, int out_size, void* d_ws, size_t ws_size,
                              hipStream_t stream) {
    (void)in_sizes; (void)n_in; (void)out_size; (void)ws_size;
    const float* feats  = (const float*)d_in[0];
    const int*   labels = (const int*)d_in[1];
    float*       out    = (float*)d_out;
    float*       partials = (float*)d_ws;   // 1024 floats = 4 KB of scratch

    // Saw series coefficients c_n = 2^{n/2} Gamma((d+n)/2) / Gamma(d/2) / n!,
    // d = 128, computed in double on host, passed by value (capture-safe).
    Coefs C;
    for (int n = 0; n < NT; ++n) {
        const double ln = 0.5 * n * std::log(2.0)
                        + std::lgamma((128.0 + n) / 2.0)
                        - std::lgamma(64.0)
                        - std::lgamma(n + 1.0);
        C.c[n] = (float)std::exp(ln);
    }

    // 8 threads/row * 32768 rows / 256 threads = 1024 blocks (4 blocks/CU)
    agd_partial_kernel<<<1024, 256, 0, stream>>>(feats, labels, partials, C);
    agd_reduce_kernel<<<1, 256, 0, stream>>>(partials, out);
}